// Round 1
// baseline (3484.552 us; speedup 1.0000x reference)
//
#include <hip/hip_runtime.h>

// Problem geometry (fixed by the reference).
#define BB 16
#define HH 540
#define WW 960
static constexpr int HW = HH * WW;          // 518400

// ---------------------------------------------------------------------------
// Scatter kernel: one thread per source pixel. Computes the depth weight and
// bilinear splat into acc (layout B x H x W x 3 interleaved so the three
// channel atomics of one corner share a cacheline).
// ---------------------------------------------------------------------------
__global__ __launch_bounds__(256) void splat_kernel(
    const float* __restrict__ back_flow,   // (B,2,H,W)
    const float* __restrict__ flowBC,      // (B,2,H,W)
    const float* __restrict__ depth,       // (B,1,H,W)
    float* __restrict__ acc)               // (B,H,W,3)
{
    int t = blockIdx.x * blockDim.x + threadIdx.x;
    int b = blockIdx.y;
    if (t >= HW) return;

    int y = t / WW;
    int x = t - y * WW;

    const float* bfp = back_flow + (size_t)b * 2 * HW;
    const float* fcp = flowBC    + (size_t)b * 2 * HW;

    float tx = (float)x + bfp[t];
    float ty = (float)y + bfp[t + HW];

    float dw = expf(-depth[(size_t)b * HW + t]);
    float v0 = fcp[t]      * dw;
    float v1 = fcp[t + HW] * dw;
    float v2 = dw;

    float x0f = floorf(tx);
    float y0f = floorf(ty);
    int   x0  = (int)x0f;
    int   y0  = (int)y0f;
    float fx  = tx - x0f;
    float fy  = ty - y0f;

    float wx[2] = {1.0f - fx, fx};
    float wy[2] = {1.0f - fy, fy};

    float* accb = acc + (size_t)b * HW * 3;

#pragma unroll
    for (int oy = 0; oy < 2; ++oy) {
        int yi = y0 + oy;
        if (yi < 0 || yi >= HH) continue;
#pragma unroll
        for (int ox = 0; ox < 2; ++ox) {
            int xi = x0 + ox;
            if (xi < 0 || xi >= WW) continue;
            float wgt = wx[ox] * wy[oy];
            if (wgt == 0.0f) continue;   // reference adds exact zeros here
            float* p = accb + ((size_t)yi * WW + xi) * 3;
            atomicAdd(p + 0, v0 * wgt);
            atomicAdd(p + 1, v1 * wgt);
            atomicAdd(p + 2, v2 * wgt);
        }
    }
}

// ---------------------------------------------------------------------------
// Finalize: warped = den > eps ? acc/den : 0 ; out = warped + flowAB
// ---------------------------------------------------------------------------
__global__ __launch_bounds__(256) void finalize_kernel(
    const float* __restrict__ acc,     // (B,H,W,3)
    const float* __restrict__ flowAB,  // (B,2,H,W)
    float* __restrict__ out)           // (B,2,H,W)
{
    int t = blockIdx.x * blockDim.x + threadIdx.x;
    int b = blockIdx.y;
    if (t >= HW) return;

    const float* p = acc + ((size_t)b * HW + t) * 3;
    float a0  = p[0];
    float a1  = p[1];
    float den = p[2];
    // den > eps  -> acc/max(den,eps) == acc/den ; else 0
    float inv = (den > 1e-6f) ? (1.0f / den) : 0.0f;

    size_t o = (size_t)b * 2 * HW + t;
    out[o]       = a0 * inv + flowAB[o];
    out[o + HW]  = a1 * inv + flowAB[o + HW];
}

extern "C" void kernel_launch(void* const* d_in, const int* in_sizes, int n_in,
                              void* d_out, int out_size, void* d_ws, size_t ws_size,
                              hipStream_t stream) {
    const float* flowAB    = (const float*)d_in[0];
    const float* back_flow = (const float*)d_in[1];
    const float* flowBC    = (const float*)d_in[2];
    const float* depth     = (const float*)d_in[3];
    float* out = (float*)d_out;
    float* acc = (float*)d_ws;

    size_t acc_bytes = (size_t)BB * HW * 3 * sizeof(float);
    hipMemsetAsync(acc, 0, acc_bytes, stream);

    dim3 block(256);
    dim3 grid((HW + 255) / 256, BB);
    splat_kernel<<<grid, block, 0, stream>>>(back_flow, flowBC, depth, acc);
    finalize_kernel<<<grid, block, 0, stream>>>(acc, flowAB, out);
}

// Round 3
// 603.034 us; speedup vs baseline: 5.7784x; 5.7784x over previous
//
#include <hip/hip_runtime.h>

// Problem geometry (fixed by the reference).
#define BB 16
#define HH 540
#define WW 960
static constexpr int HW = HH * WW;          // 518400

// Tiled-privatization geometry.
#define TW 64
#define TH 32
#define HALO 8
#define RW (TW + 2 * HALO)          // 80
#define RH (TH + 2 * HALO)          // 48
#define RCELLS (RW * RH)            // 3840
#define RFLOATS (RCELLS * 3)        // 11520
#define TCX 15                      // 960/64
#define TCY 17                      // ceil(540/32)

// ---------------------------------------------------------------------------
// Fast path: per-tile LDS accumulation, non-atomic region store.
// Each block owns a TWxTH source tile; all splats land in the halo'd LDS
// region (LDS atomics). Region is stored contiguously per tile.
// ---------------------------------------------------------------------------
__global__ __launch_bounds__(256) void splat_tile_kernel(
    const float* __restrict__ back_flow,   // (B,2,H,W)
    const float* __restrict__ flowBC,      // (B,2,H,W)
    const float* __restrict__ depth,       // (B,1,H,W)
    float* __restrict__ regions)           // (B,TCY,TCX,RH,RW,3)
{
    __shared__ float lacc[RFLOATS];

    const int tcx = blockIdx.x;
    const int tcy = blockIdx.y;
    const int b   = blockIdx.z;
    const int tx0 = tcx * TW;
    const int ty0 = tcy * TH;

    for (int i = threadIdx.x; i < RFLOATS; i += 256) lacc[i] = 0.0f;
    __syncthreads();

    const float* bfp = back_flow + (size_t)b * 2 * HW;
    const float* fcp = flowBC    + (size_t)b * 2 * HW;
    const float* dp  = depth     + (size_t)b * HW;

    for (int p = threadIdx.x; p < TW * TH; p += 256) {
        const int lx = p & (TW - 1);
        const int ly = p >> 6;               // log2(TW)
        const int x  = tx0 + lx;
        const int y  = ty0 + ly;
        if (y >= HH) continue;               // partial last tile row
        const int t = y * WW + x;

        const float txf = (float)x + bfp[t];
        const float tyf = (float)y + bfp[t + HW];
        const float dw  = expf(-dp[t]);
        const float v0  = fcp[t]      * dw;
        const float v1  = fcp[t + HW] * dw;
        const float v2  = dw;

        const float x0f = floorf(txf);
        const float y0f = floorf(tyf);
        const int   x0  = (int)x0f;
        const int   y0  = (int)y0f;
        const float fx  = txf - x0f;
        const float fy  = tyf - y0f;

        const int rx0 = x0 - tx0 + HALO;
        const int ry0 = y0 - ty0 + HALO;

#pragma unroll
        for (int oy = 0; oy < 2; ++oy) {
            const int yi = y0 + oy;
            if (yi < 0 || yi >= HH) continue;
            const float wyv = oy ? fy : 1.0f - fy;
#pragma unroll
            for (int ox = 0; ox < 2; ++ox) {
                const int xi = x0 + ox;
                if (xi < 0 || xi >= WW) continue;
                const float w = (ox ? fx : 1.0f - fx) * wyv;
                if (w == 0.0f) continue;     // exact-zero adds are no-ops
                const int rx = rx0 + ox;
                const int ry = ry0 + oy;
                if (rx >= 0 && rx < RW && ry >= 0 && ry < RH) {
                    float* lp = &lacc[(ry * RW + rx) * 3];
                    atomicAdd(lp + 0, v0 * w);
                    atomicAdd(lp + 1, v1 * w);
                    atomicAdd(lp + 2, v2 * w);
                } else {
                    // ~zero-probability outlier (|disp| > 8): add into the
                    // owning tile's interior cell in global memory.
                    const int otcx = xi / TW;
                    const int otcy = yi / TH;
                    const size_t base =
                        (((size_t)b * TCY + otcy) * TCX + otcx) * (size_t)RFLOATS;
                    const int orx = xi - otcx * TW + HALO;
                    const int ory = yi - otcy * TH + HALO;
                    float* gp = regions + base + (size_t)(ory * RW + orx) * 3;
                    atomicAdd(gp + 0, v0 * w);
                    atomicAdd(gp + 1, v1 * w);
                    atomicAdd(gp + 2, v2 * w);
                }
            }
        }
    }

    __syncthreads();
    const size_t base = (((size_t)b * TCY + tcy) * TCX + tcx) * (size_t)RFLOATS;
    for (int i = threadIdx.x; i < RFLOATS; i += 256)
        regions[base + i] = lacc[i];
}

// ---------------------------------------------------------------------------
// Finalize (fast path): gather from the <=9 tile regions covering the pixel.
// ---------------------------------------------------------------------------
__global__ __launch_bounds__(256) void finalize_tiles_kernel(
    const float* __restrict__ regions,
    const float* __restrict__ flowAB,
    float* __restrict__ out)
{
    const int t = blockIdx.x * 256 + threadIdx.x;
    const int b = blockIdx.y;
    if (t >= HW) return;
    const int y = t / WW;
    const int x = t - y * WW;
    const int ctx = x / TW;
    const int cty = y / TH;

    float a0 = 0.0f, a1 = 0.0f, a2 = 0.0f;
#pragma unroll
    for (int dy = -1; dy <= 1; ++dy) {
        const int tcy = cty + dy;
        if (tcy < 0 || tcy >= TCY) continue;
        const int ry = y - tcy * TH + HALO;
        if (ry < 0 || ry >= RH) continue;
#pragma unroll
        for (int dx = -1; dx <= 1; ++dx) {
            const int tcx = ctx + dx;
            if (tcx < 0 || tcx >= TCX) continue;
            const int rx = x - tcx * TW + HALO;
            if (rx < 0 || rx >= RW) continue;
            const float* p = regions +
                ((((size_t)b * TCY + tcy) * TCX + tcx) * (size_t)RCELLS +
                 (size_t)(ry * RW + rx)) * 3;
            a0 += p[0];
            a1 += p[1];
            a2 += p[2];
        }
    }

    const float inv = (a2 > 1e-6f) ? (1.0f / a2) : 0.0f;
    const size_t o = (size_t)b * 2 * HW + t;
    out[o]      = a0 * inv + flowAB[o];
    out[o + HW] = a1 * inv + flowAB[o + HW];
}

// ---------------------------------------------------------------------------
// Fallback path (round-1): global atomics. Used only if ws_size is too small.
// ---------------------------------------------------------------------------
__global__ __launch_bounds__(256) void splat_kernel(
    const float* __restrict__ back_flow,
    const float* __restrict__ flowBC,
    const float* __restrict__ depth,
    float* __restrict__ acc)
{
    int t = blockIdx.x * blockDim.x + threadIdx.x;
    int b = blockIdx.y;
    if (t >= HW) return;
    int y = t / WW;
    int x = t - y * WW;
    const float* bfp = back_flow + (size_t)b * 2 * HW;
    const float* fcp = flowBC    + (size_t)b * 2 * HW;
    float tx = (float)x + bfp[t];
    float ty = (float)y + bfp[t + HW];
    float dw = expf(-depth[(size_t)b * HW + t]);
    float v0 = fcp[t] * dw;
    float v1 = fcp[t + HW] * dw;
    float x0f = floorf(tx), y0f = floorf(ty);
    int x0 = (int)x0f, y0 = (int)y0f;
    float fx = tx - x0f, fy = ty - y0f;
    float wx[2] = {1.0f - fx, fx};
    float wy[2] = {1.0f - fy, fy};
    float* accb = acc + (size_t)b * HW * 3;
#pragma unroll
    for (int oy = 0; oy < 2; ++oy) {
        int yi = y0 + oy;
        if (yi < 0 || yi >= HH) continue;
#pragma unroll
        for (int ox = 0; ox < 2; ++ox) {
            int xi = x0 + ox;
            if (xi < 0 || xi >= WW) continue;
            float wgt = wx[ox] * wy[oy];
            if (wgt == 0.0f) continue;
            float* p = accb + ((size_t)yi * WW + xi) * 3;
            atomicAdd(p + 0, v0 * wgt);
            atomicAdd(p + 1, v1 * wgt);
            atomicAdd(p + 2, dw * wgt);
        }
    }
}

__global__ __launch_bounds__(256) void finalize_kernel(
    const float* __restrict__ acc,
    const float* __restrict__ flowAB,
    float* __restrict__ out)
{
    int t = blockIdx.x * blockDim.x + threadIdx.x;
    int b = blockIdx.y;
    if (t >= HW) return;
    const float* p = acc + ((size_t)b * HW + t) * 3;
    float a0 = p[0], a1 = p[1], den = p[2];
    float inv = (den > 1e-6f) ? (1.0f / den) : 0.0f;
    size_t o = (size_t)b * 2 * HW + t;
    out[o]      = a0 * inv + flowAB[o];
    out[o + HW] = a1 * inv + flowAB[o + HW];
}

extern "C" void kernel_launch(void* const* d_in, const int* in_sizes, int n_in,
                              void* d_out, int out_size, void* d_ws, size_t ws_size,
                              hipStream_t stream) {
    const float* flowAB    = (const float*)d_in[0];
    const float* back_flow = (const float*)d_in[1];
    const float* flowBC    = (const float*)d_in[2];
    const float* depth     = (const float*)d_in[3];
    float* out = (float*)d_out;

    const size_t regions_bytes =
        (size_t)BB * TCY * TCX * (size_t)RFLOATS * sizeof(float);   // ~188 MB

    if (ws_size >= regions_bytes) {
        float* regions = (float*)d_ws;
        dim3 sgrid(TCX, TCY, BB);
        splat_tile_kernel<<<sgrid, 256, 0, stream>>>(back_flow, flowBC, depth, regions);
        dim3 fgrid((HW + 255) / 256, BB);
        finalize_tiles_kernel<<<fgrid, 256, 0, stream>>>(regions, flowAB, out);
    } else {
        float* acc = (float*)d_ws;
        size_t acc_bytes = (size_t)BB * HW * 3 * sizeof(float);
        hipMemsetAsync(acc, 0, acc_bytes, stream);
        dim3 grid((HW + 255) / 256, BB);
        splat_kernel<<<grid, 256, 0, stream>>>(back_flow, flowBC, depth, acc);
        finalize_kernel<<<grid, 256, 0, stream>>>(acc, flowAB, out);
    }
}

// Round 5
// 601.326 us; speedup vs baseline: 5.7948x; 1.0028x over previous
//
#include <hip/hip_runtime.h>

// Problem geometry (fixed by the reference).
#define BB 16
#define HH 540
#define WW 960
static constexpr int HW = HH * WW;          // 518400

// Tiled-privatization geometry.
#define TW 64
#define TH 32
#define HALO 8
#define RW (TW + 2 * HALO)          // 80
#define RH (TH + 2 * HALO)          // 48
#define RCELLS (RW * RH)            // 3840
#define RFLOATS (RCELLS * 3)        // 11520
#define TCX 15                      // 960/64
#define TCY 17                      // ceil(540/32)

// ---------------------------------------------------------------------------
// Fast path: per-tile LDS float accumulation using unsafeAtomicAdd, which
// lowers to single-instruction ds_add_f32 (plain float atomicAdd emits a CAS
// loop without -munsafe-fp-atomics -> 2 dependent LDS round-trips per add).
// ---------------------------------------------------------------------------
__global__ __launch_bounds__(256) void splat_tile_kernel(
    const float* __restrict__ back_flow,   // (B,2,H,W)
    const float* __restrict__ flowBC,      // (B,2,H,W)
    const float* __restrict__ depth,       // (B,1,H,W)
    float* __restrict__ regions)           // (B,TCY,TCX,RH,RW,3)
{
    __shared__ float lacc[RFLOATS];

    const int tcx = blockIdx.x;
    const int tcy = blockIdx.y;
    const int b   = blockIdx.z;
    const int tx0 = tcx * TW;
    const int ty0 = tcy * TH;

    for (int i = threadIdx.x; i < RFLOATS; i += 256) lacc[i] = 0.0f;
    __syncthreads();

    const float* bfp = back_flow + (size_t)b * 2 * HW;
    const float* fcp = flowBC    + (size_t)b * 2 * HW;
    const float* dp  = depth     + (size_t)b * HW;

    for (int p = threadIdx.x; p < TW * TH; p += 256) {
        const int lx = p & (TW - 1);
        const int ly = p >> 6;               // log2(TW)
        const int x  = tx0 + lx;
        const int y  = ty0 + ly;
        if (y >= HH) continue;               // partial last tile row
        const int t = y * WW + x;

        const float txf = (float)x + bfp[t];
        const float tyf = (float)y + bfp[t + HW];
        const float dw  = expf(-dp[t]);
        const float v0  = fcp[t]      * dw;
        const float v1  = fcp[t + HW] * dw;
        const float v2  = dw;

        const float x0f = floorf(txf);
        const float y0f = floorf(tyf);
        const int   x0  = (int)x0f;
        const int   y0  = (int)y0f;
        const float fx  = txf - x0f;
        const float fy  = tyf - y0f;

        const int rx0 = x0 - tx0 + HALO;
        const int ry0 = y0 - ty0 + HALO;

#pragma unroll
        for (int oy = 0; oy < 2; ++oy) {
            const int yi = y0 + oy;
            if (yi < 0 || yi >= HH) continue;
            const float wyv = oy ? fy : 1.0f - fy;
#pragma unroll
            for (int ox = 0; ox < 2; ++ox) {
                const int xi = x0 + ox;
                if (xi < 0 || xi >= WW) continue;
                const float w = (ox ? fx : 1.0f - fx) * wyv;
                if (w == 0.0f) continue;     // exact-zero adds are no-ops
                const int rx = rx0 + ox;
                const int ry = ry0 + oy;
                if (rx >= 0 && rx < RW && ry >= 0 && ry < RH) {
                    float* lp = &lacc[(ry * RW + rx) * 3];
                    unsafeAtomicAdd(lp + 0, v0 * w);
                    unsafeAtomicAdd(lp + 1, v1 * w);
                    unsafeAtomicAdd(lp + 2, v2 * w);
                } else {
                    // ~zero-probability outlier (|disp| > 8): add into the
                    // owning tile's interior cell in global memory (float).
                    const int otcx = xi / TW;
                    const int otcy = yi / TH;
                    const size_t base =
                        (((size_t)b * TCY + otcy) * TCX + otcx) * (size_t)RFLOATS;
                    const int orx = xi - otcx * TW + HALO;
                    const int ory = yi - otcy * TH + HALO;
                    float* gp = regions + base + (size_t)(ory * RW + orx) * 3;
                    unsafeAtomicAdd(gp + 0, v0 * w);
                    unsafeAtomicAdd(gp + 1, v1 * w);
                    unsafeAtomicAdd(gp + 2, v2 * w);
                }
            }
        }
    }

    __syncthreads();
    const size_t base = (((size_t)b * TCY + tcy) * TCX + tcx) * (size_t)RFLOATS;
    for (int i = threadIdx.x; i < RFLOATS; i += 256)
        regions[base + i] = lacc[i];
}

// ---------------------------------------------------------------------------
// Finalize (fast path): gather from the <=9 tile regions covering the pixel.
// ---------------------------------------------------------------------------
__global__ __launch_bounds__(256) void finalize_tiles_kernel(
    const float* __restrict__ regions,
    const float* __restrict__ flowAB,
    float* __restrict__ out)
{
    const int t = blockIdx.x * 256 + threadIdx.x;
    const int b = blockIdx.y;
    if (t >= HW) return;
    const int y = t / WW;
    const int x = t - y * WW;
    const int ctx = x / TW;
    const int cty = y / TH;

    float a0 = 0.0f, a1 = 0.0f, a2 = 0.0f;
#pragma unroll
    for (int dy = -1; dy <= 1; ++dy) {
        const int tcy = cty + dy;
        if (tcy < 0 || tcy >= TCY) continue;
        const int ry = y - tcy * TH + HALO;
        if (ry < 0 || ry >= RH) continue;
#pragma unroll
        for (int dx = -1; dx <= 1; ++dx) {
            const int tcx = ctx + dx;
            if (tcx < 0 || tcx >= TCX) continue;
            const int rx = x - tcx * TW + HALO;
            if (rx < 0 || rx >= RW) continue;
            const float* p = regions +
                ((((size_t)b * TCY + tcy) * TCX + tcx) * (size_t)RCELLS +
                 (size_t)(ry * RW + rx)) * 3;
            a0 += p[0];
            a1 += p[1];
            a2 += p[2];
        }
    }

    const float inv = (a2 > 1e-6f) ? (1.0f / a2) : 0.0f;
    const size_t o = (size_t)b * 2 * HW + t;
    out[o]      = a0 * inv + flowAB[o];
    out[o + HW] = a1 * inv + flowAB[o + HW];
}

// ---------------------------------------------------------------------------
// Fallback path (round-1): global atomics. Used only if ws_size is too small.
// ---------------------------------------------------------------------------
__global__ __launch_bounds__(256) void splat_kernel(
    const float* __restrict__ back_flow,
    const float* __restrict__ flowBC,
    const float* __restrict__ depth,
    float* __restrict__ acc)
{
    int t = blockIdx.x * blockDim.x + threadIdx.x;
    int b = blockIdx.y;
    if (t >= HW) return;
    int y = t / WW;
    int x = t - y * WW;
    const float* bfp = back_flow + (size_t)b * 2 * HW;
    const float* fcp = flowBC    + (size_t)b * 2 * HW;
    float tx = (float)x + bfp[t];
    float ty = (float)y + bfp[t + HW];
    float dw = expf(-depth[(size_t)b * HW + t]);
    float v0 = fcp[t] * dw;
    float v1 = fcp[t + HW] * dw;
    float x0f = floorf(tx), y0f = floorf(ty);
    int x0 = (int)x0f, y0 = (int)y0f;
    float fx = tx - x0f, fy = ty - y0f;
    float wx[2] = {1.0f - fx, fx};
    float wy[2] = {1.0f - fy, fy};
    float* accb = acc + (size_t)b * HW * 3;
#pragma unroll
    for (int oy = 0; oy < 2; ++oy) {
        int yi = y0 + oy;
        if (yi < 0 || yi >= HH) continue;
#pragma unroll
        for (int ox = 0; ox < 2; ++ox) {
            int xi = x0 + ox;
            if (xi < 0 || xi >= WW) continue;
            float wgt = wx[ox] * wy[oy];
            if (wgt == 0.0f) continue;
            float* p = accb + ((size_t)yi * WW + xi) * 3;
            atomicAdd(p + 0, v0 * wgt);
            atomicAdd(p + 1, v1 * wgt);
            atomicAdd(p + 2, dw * wgt);
        }
    }
}

__global__ __launch_bounds__(256) void finalize_kernel(
    const float* __restrict__ acc,
    const float* __restrict__ flowAB,
    float* __restrict__ out)
{
    int t = blockIdx.x * blockDim.x + threadIdx.x;
    int b = blockIdx.y;
    if (t >= HW) return;
    const float* p = acc + ((size_t)b * HW + t) * 3;
    float a0 = p[0], a1 = p[1], den = p[2];
    float inv = (den > 1e-6f) ? (1.0f / den) : 0.0f;
    size_t o = (size_t)b * 2 * HW + t;
    out[o]      = a0 * inv + flowAB[o];
    out[o + HW] = a1 * inv + flowAB[o + HW];
}

extern "C" void kernel_launch(void* const* d_in, const int* in_sizes, int n_in,
                              void* d_out, int out_size, void* d_ws, size_t ws_size,
                              hipStream_t stream) {
    const float* flowAB    = (const float*)d_in[0];
    const float* back_flow = (const float*)d_in[1];
    const float* flowBC    = (const float*)d_in[2];
    const float* depth     = (const float*)d_in[3];
    float* out = (float*)d_out;

    const size_t regions_bytes =
        (size_t)BB * TCY * TCX * (size_t)RFLOATS * sizeof(float);   // ~188 MB

    if (ws_size >= regions_bytes) {
        float* regions = (float*)d_ws;
        dim3 sgrid(TCX, TCY, BB);
        splat_tile_kernel<<<sgrid, 256, 0, stream>>>(back_flow, flowBC, depth, regions);
        dim3 fgrid((HW + 255) / 256, BB);
        finalize_tiles_kernel<<<fgrid, 256, 0, stream>>>(regions, flowAB, out);
    } else {
        float* acc = (float*)d_ws;
        size_t acc_bytes = (size_t)BB * HW * 3 * sizeof(float);
        hipMemsetAsync(acc, 0, acc_bytes, stream);
        dim3 grid((HW + 255) / 256, BB);
        splat_kernel<<<grid, 256, 0, stream>>>(back_flow, flowBC, depth, acc);
        finalize_kernel<<<grid, 256, 0, stream>>>(acc, flowAB, out);
    }
}